// Round 9
// baseline (472.034 us; speedup 1.0000x reference)
//
#include <hip/hip_runtime.h>
#include <hip/hip_bf16.h>

typedef __hip_bfloat16 bf16;

// Problem constants
#define NB 32      // batch
#define NSEQ 540   // sequence length
#define ND 512     // model dim
#define NH 8       // heads
#define NDH 64     // head dim
#define NHB 256    // NH*NB
#define NM 17280   // NB*NSEQ
#define NPOS 1079  // 2*539+1
#define VTP 544    // vt row pitch (16B-aligned rows for all dh)

// MFMA types (gfx950 v_mfma_f32_16x16x32_bf16)
typedef __bf16 v8bf __attribute__((ext_vector_type(8)));
typedef float f32x4 __attribute__((ext_vector_type(4)));

union U8 {
  uint4 u;
  unsigned short s[8];
  v8bf v;
};

__device__ __forceinline__ unsigned short f2b(float x) {  // RNE fp32->bf16 bits
  union { float f; unsigned u; } c;
  c.f = x;
  const unsigned r = c.u + 0x7fffu + ((c.u >> 16) & 1u);
  return (unsigned short)(r >> 16);
}

__device__ __forceinline__ float b2f16(unsigned short s) {
  return __uint_as_float(((unsigned)s) << 16);
}

// 16 fp32 (global) -> 16 bf16 -> 32B dst (LDS or global), dst 16B-aligned
__device__ __forceinline__ void cvt16(const float* __restrict__ p,
                                      unsigned short* __restrict__ dst) {
  unsigned short s[16];
#pragma unroll
  for (int i = 0; i < 4; i++) {
    const float4 v = *(const float4*)(p + i * 4);
    s[i * 4 + 0] = f2b(v.x);
    s[i * 4 + 1] = f2b(v.y);
    s[i * 4 + 2] = f2b(v.z);
    s[i * 4 + 3] = f2b(v.w);
  }
  *(uint4*)dst = *(uint4*)s;
  *(uint4*)(dst + 8) = *(uint4*)(s + 8);
}

// ---------------------------------------------------------------------------
// K0a: one-time pos fp32 -> bf16
// ---------------------------------------------------------------------------
__global__ __launch_bounds__(256) void pos_cvt(const float* __restrict__ pos,
                                              unsigned short* __restrict__ posb) {
  const int i = blockIdx.x * 256 + threadIdx.x;
  if (i < NPOS * NDH) posb[i] = f2b(pos[i]);
}

// ---------------------------------------------------------------------------
// K0b: one-time weight cvt+transpose: W[k][n] fp32 -> Wt[n][k] bf16, x4 weights
// ---------------------------------------------------------------------------
__global__ __launch_bounds__(256) void wcvt(
    const float* __restrict__ Wq, const float* __restrict__ Wk,
    const float* __restrict__ Wv, const float* __restrict__ Wh,
    unsigned short* __restrict__ Wt) {
  __shared__ unsigned short T[64][72];
  const int tid = threadIdx.x;
  const int sel = blockIdx.z;
  const float* W = (sel == 0) ? Wq : (sel == 1) ? Wk : (sel == 2) ? Wv : Wh;
  unsigned short* out = Wt + (size_t)sel * ND * ND;
  const int k0 = blockIdx.x * 64, n0 = blockIdx.y * 64;
  const int r = tid >> 2, g = tid & 3;
  cvt16(W + (size_t)(k0 + r) * ND + n0 + g * 16, &T[r][g * 16]);
  __syncthreads();
  unsigned short s[16];
#pragma unroll
  for (int j = 0; j < 16; j++) s[j] = T[g * 16 + j][r];
  unsigned short* dst = out + (size_t)(n0 + r) * ND + k0 + g * 16;
  *(uint4*)dst = *(uint4*)s;
  *(uint4*)(dst + 8) = *(uint4*)(s + 8);
}

// ---------------------------------------------------------------------------
// MFMA GEMM core: 128x128 tile, K=512, BK=32, 4 waves (2x2 of 64x64).
// ---------------------------------------------------------------------------
#define GEMM_CORE(APTR)                                                           \
  for (int k0 = 0; k0 < 512; k0 += 32) {                                          \
    __syncthreads();                                                              \
    cvt16(APTR + (size_t)(m0 + srow) * ND + k0 + sh, &As[srow][sh]);              \
    {                                                                             \
      const unsigned short* bp = Bt + (size_t)(n0 + srow) * ND + k0 + sh;         \
      *(uint4*)&Bs[srow][sh] = *(const uint4*)bp;                                 \
      *(uint4*)&Bs[srow][sh + 8] = *(const uint4*)(bp + 8);                       \
    }                                                                             \
    __syncthreads();                                                              \
    U8 af[4], bfr[4];                                                             \
    _Pragma("unroll")                                                             \
    for (int mi = 0; mi < 4; mi++)                                                \
      af[mi].u = *(const uint4*)&As[wr * 64 + mi * 16 + l15][quad * 8];           \
    _Pragma("unroll")                                                             \
    for (int ni = 0; ni < 4; ni++)                                                \
      bfr[ni].u = *(const uint4*)&Bs[wc * 64 + ni * 16 + l15][quad * 8];          \
    _Pragma("unroll")                                                             \
    for (int mi = 0; mi < 4; mi++)                                                \
      _Pragma("unroll")                                                           \
      for (int ni = 0; ni < 4; ni++)                                              \
        acc[mi][ni] = __builtin_amdgcn_mfma_f32_16x16x32_bf16(                    \
            af[mi].v, bfr[ni].v, acc[mi][ni], 0, 0, 0);                           \
  }

// ---------------------------------------------------------------------------
// K1: QKV projection via MFMA. X[17280,512] fp32 @ Wt^T + bias.
// sel 0/1 -> head-major q/k bf16; sel 2 -> transposed vt[x][dh][VTP] bf16.
// ---------------------------------------------------------------------------
__global__ __launch_bounds__(256, 2) void qkv_mfma(
    const float* __restrict__ X, const unsigned short* __restrict__ Wt,
    const float* __restrict__ bq, const float* __restrict__ bk,
    const float* __restrict__ bv,
    bf16* __restrict__ qh, bf16* __restrict__ kh, bf16* __restrict__ vt) {
  __shared__ unsigned short As[128][40];
  __shared__ unsigned short Bs[128][40];
  const int tid = threadIdx.x;
  const int sel = blockIdx.z;
  const unsigned short* Bt = Wt + (size_t)sel * ND * ND;
  const float* bias = (sel == 0) ? bq : (sel == 1) ? bk : bv;
  const int m0 = blockIdx.y * 128, n0 = blockIdx.x * 128;
  const int lane = tid & 63, w = tid >> 6;
  const int wr = w & 1, wc = w >> 1;
  const int l15 = lane & 15, quad = lane >> 4;
  const int srow = tid >> 1, sh = (tid & 1) * 16;

  f32x4 acc[4][4];
#pragma unroll
  for (int mi = 0; mi < 4; mi++)
#pragma unroll
    for (int ni = 0; ni < 4; ni++) acc[mi][ni] = (f32x4){0.f, 0.f, 0.f, 0.f};

  GEMM_CORE(X)

  if (sel != 2) {
    unsigned short* o = (unsigned short*)((sel == 0) ? qh : kh);
#pragma unroll
    for (int mi = 0; mi < 4; mi++) {
      const int m = m0 + wr * 64 + mi * 16 + quad * 4;  // mult of 4; 540%4==0
      const int bidx = m / NSEQ;
      const int seq0 = m - bidx * NSEQ;
#pragma unroll
      for (int ni = 0; ni < 4; ni++) {
        const int n = n0 + wc * 64 + ni * 16 + l15;
        const int h = n >> 6, dh = n & 63;
        const float bsv = bias[n];
        const size_t base = (((size_t)(h * NB + bidx)) * NSEQ + seq0) * NDH + dh;
#pragma unroll
        for (int i = 0; i < 4; i++)
          o[base + (size_t)i * NDH] = f2b(acc[mi][ni][i] + bsv);
      }
    }
  } else {
    unsigned short* o = (unsigned short*)vt;
#pragma unroll
    for (int mi = 0; mi < 4; mi++) {
      const int m = m0 + wr * 64 + mi * 16 + quad * 4;
      const int bidx = m / NSEQ;
      const int seq0 = m - bidx * NSEQ;  // mult of 4 -> uint2 never crosses batch
#pragma unroll
      for (int ni = 0; ni < 4; ni++) {
        const int n = n0 + wc * 64 + ni * 16 + l15;
        const int h = n >> 6, dh = n & 63;
        const float bsv = bias[n];
        unsigned short pk[4];
#pragma unroll
        for (int i = 0; i < 4; i++) pk[i] = f2b(acc[mi][ni][i] + bsv);
        *(uint2*)(o + (((size_t)(h * NB + bidx)) * NDH + dh) * VTP + seq0) =
            *(uint2*)pk;
      }
    }
  }
}

// ---------------------------------------------------------------------------
// K3: out projection via MFMA + bias + residual -> tmp fp32.
// ---------------------------------------------------------------------------
__global__ __launch_bounds__(256, 2) void out_mfma(
    const float* __restrict__ ctx, const unsigned short* __restrict__ Wht,
    const float* __restrict__ bh, const float* __restrict__ query,
    float* __restrict__ tmp) {
  __shared__ unsigned short As[128][40];
  __shared__ unsigned short Bs[128][40];
  const int tid = threadIdx.x;
  const unsigned short* Bt = Wht;
  const int m0 = blockIdx.y * 128, n0 = blockIdx.x * 128;
  const int lane = tid & 63, w = tid >> 6;
  const int wr = w & 1, wc = w >> 1;
  const int l15 = lane & 15, quad = lane >> 4;
  const int srow = tid >> 1, sh = (tid & 1) * 16;

  f32x4 acc[4][4];
#pragma unroll
  for (int mi = 0; mi < 4; mi++)
#pragma unroll
    for (int ni = 0; ni < 4; ni++) acc[mi][ni] = (f32x4){0.f, 0.f, 0.f, 0.f};

  GEMM_CORE(ctx)

#pragma unroll
  for (int mi = 0; mi < 4; mi++) {
    const int m = m0 + wr * 64 + mi * 16 + quad * 4;
#pragma unroll
    for (int ni = 0; ni < 4; ni++) {
      const int n = n0 + wc * 64 + ni * 16 + l15;
      const float bsv = bh[n];
#pragma unroll
      for (int i = 0; i < 4; i++) {
        const size_t off = (size_t)(m + i) * ND + n;
        tmp[off] = acc[mi][ni][i] + bsv + query[off];
      }
    }
  }
}

// ---------------------------------------------------------------------------
// K2: attention v5: barrier-free phase A + register softmax.
// Block = (q-tile 16, head-batch x), 4 waves. Wave w owns key cols
// [w*16, w*16+16) of each 64-key tile.
// Phase A (0 barriers, fully unrolled): QK B-frags + BOTH pos sub-tiles the
// wave needs (cols w*16..w*16+31) loaded straight from global; the Shaw term
// T[qq][kk+15-qq] gathered in-register via ds_bpermute. Scores live in VGPRs.
// Softmax: shfl_xor reductions within quads + one 16x4 LDS exchange per
// max/sum (2 barriers total in the kernel). Masked cols never enter exp
// (NaN-safe vs unclamped OOB reads, which all stay inside ws).
// Phase C: P (bf16, LDS) as A-frags, vt rows as B-frags, 18 unrolled MFMAs;
// 1/l folded into the epilogue from register inv[i].
// ---------------------------------------------------------------------------
#define PW 584  // P row stride (ushorts)

__global__ __launch_bounds__(256, 4) void attn(
    const bf16* __restrict__ qh, const bf16* __restrict__ kh,
    const bf16* __restrict__ vt, const unsigned short* __restrict__ posb,
    const int* __restrict__ vlen, float* __restrict__ ctx) {
  __shared__ unsigned short P[16][PW];  // 18.7 KB
  __shared__ float redm[16][4];
  __shared__ float reds[16][4];

  const int tid = threadIdx.x;
  const int lane = tid & 63;
  const int w = tid >> 6;
  const int l15 = lane & 15;
  const int quad = lane >> 4;
  const int qb = blockIdx.x;
  const int x = blockIdx.y;
  const int b = x & 31, h = x >> 5;
  const int q0 = qb * 16;
  const int valid = vlen[b];
  const bf16* qbase = qh + (size_t)x * NSEQ * NDH;
  const unsigned short* kbase = (const unsigned short*)(kh + (size_t)x * NSEQ * NDH);
  const unsigned short* vbase = (const unsigned short*)(vt + (size_t)x * NDH * VTP);

  // Q A-fragments, zero-filled rows past NSEQ
  U8 aq0, aq1;
  {
    const int q = q0 + l15;
    if (q < NSEQ) {
      aq0.u = *(const uint4*)(qbase + (size_t)q * NDH + quad * 8);
      aq1.u = *(const uint4*)(qbase + (size_t)q * NDH + 32 + quad * 8);
    } else {
      aq0.u = make_uint4(0, 0, 0, 0);
      aq1.u = make_uint4(0, 0, 0, 0);
    }
  }

  const int colbase = w * 16 + l15;  // this lane's key column within a tile

  // -------- phase A: scores in registers, no barriers --------
  float sc[9][4];
#pragma unroll
  for (int kt = 0; kt < 9; kt++) {
    const int k0 = kt * 64;
    const long key = k0 + colbase;  // OOB rows (>=540) stay in ws; masked later
    U8 bk0, bk1;
    bk0.u = *(const uint4*)(kbase + key * NDH + quad * 8);
    bk1.u = *(const uint4*)(kbase + key * NDH + 32 + quad * 8);
    const long r0 = (long)k0 - q0 + 524;  // pos row of (q=q0+15, k=k0)
    const long prA = r0 + w * 16 + l15;   // cols w*16..+15
    const long prB = prA + 16;            // cols w*16+16..+31
    U8 pa0, pa1, pb0, pb1;
    pa0.u = *(const uint4*)(posb + prA * NDH + quad * 8);
    pa1.u = *(const uint4*)(posb + prA * NDH + 32 + quad * 8);
    pb0.u = *(const uint4*)(posb + prB * NDH + quad * 8);
    pb1.u = *(const uint4*)(posb + prB * NDH + 32 + quad * 8);

    f32x4 accqk = {0.f, 0.f, 0.f, 0.f};
    accqk = __builtin_amdgcn_mfma_f32_16x16x32_bf16(aq0.v, bk0.v, accqk, 0, 0, 0);
    accqk = __builtin_amdgcn_mfma_f32_16x16x32_bf16(aq1.v, bk1.v, accqk, 0, 0, 0);
    f32x4 accTa = {0.f, 0.f, 0.f, 0.f};
    accTa = __builtin_amdgcn_mfma_f32_16x16x32_bf16(aq0.v, pa0.v, accTa, 0, 0, 0);
    accTa = __builtin_amdgcn_mfma_f32_16x16x32_bf16(aq1.v, pa1.v, accTa, 0, 0, 0);
    f32x4 accTb = {0.f, 0.f, 0.f, 0.f};
    accTb = __builtin_amdgcn_mfma_f32_16x16x32_bf16(aq0.v, pb0.v, accTb, 0, 0, 0);
    accTb = __builtin_amdgcn_mfma_f32_16x16x32_bf16(aq1.v, pb1.v, accTb, 0, 0, 0);

    // gather T[qq][kk+15-qq]: kk = w*16+l15, qq = quad*4+i ->
    // offset o = l15+15-qq in [0,30]; src lane = quad*16 + (o&15)
#pragma unroll
    for (int i = 0; i < 4; i++) {
      const int qq = quad * 4 + i;
      const int o = l15 + 15 - qq;
      const int idx = (quad * 16 + (o & 15)) << 2;
      const float ta = __int_as_float(
          __builtin_amdgcn_ds_bpermute(idx, __float_as_int(accTa[i])));
      const float tb = __int_as_float(
          __builtin_amdgcn_ds_bpermute(idx, __float_as_int(accTb[i])));
      sc[kt][i] = (accqk[i] + ((o < 16) ? ta : tb)) * 0.125f;
    }
  }

  // -------- softmax over k < valid (register-resident) --------
  float mx[4] = {-1e30f, -1e30f, -1e30f, -1e30f};
#pragma unroll
  for (int kt = 0; kt < 9; kt++)
#pragma unroll
    for (int i = 0; i < 4; i++)
      if (kt * 64 + colbase < valid) mx[i] = fmaxf(mx[i], sc[kt][i]);
#pragma unroll
  for (int msk = 1; msk < 16; msk <<= 1)
#pragma unroll
    for (int i = 0; i < 4; i++) mx[i] = fmaxf(mx[i], __shfl_xor(mx[i], msk, 16));
  if (l15 == 0) {
#pragma unroll
    for (int i = 0; i < 4; i++) redm[quad * 4 + i][w] = mx[i];
  }
  __syncthreads();
  float rowmax[4];
#pragma unroll
  for (int i = 0; i < 4; i++) {
    const float4 rm = *(const float4*)redm[quad * 4 + i];
    rowmax[i] = fmaxf(fmaxf(rm.x, rm.y), fmaxf(rm.z, rm.w));
  }

  float sm[4] = {0.f, 0.f, 0.f, 0.f};
#pragma unroll
  for (int kt = 0; kt < 9; kt++) {
    const int col = kt * 64 + colbase;
#pragma unroll
    for (int i = 0; i < 4; i++) {
      float e = 0.f;
      if (col < valid) {
        e = __expf(sc[kt][i] - rowmax[i]);
        sm[i] += e;
      }
      P[quad * 4 + i][col] = f2b(e);  // exclusion: masked/pad cols get 0
    }
  }
#pragma unroll
  for (int msk = 1; msk < 16; msk <<= 1)
#pragma unroll
    for (int i = 0; i < 4; i++) sm[i] += __shfl_xor(sm[i], msk, 16);
  if (l15 == 0) {
#pragma unroll
    for (int i = 0; i < 4; i++) reds[quad * 4 + i][w] = sm[i];
  }
  __syncthreads();  // P + reds published
  float inv[4];
#pragma unroll
  for (int i = 0; i < 4; i++) {
    const float4 rs = *(const float4*)reds[quad * 4 + i];
    inv[i] = 1.f / (rs.x + rs.y + rs.z + rs.w);
  }

  // -------- phase C: O = (P_unnorm @ V) * inv --------
  const int dh = w * 16 + l15;
  const unsigned short* vrow = vbase + (size_t)dh * VTP;
  f32x4 acco = {0.f, 0.f, 0.f, 0.f};
#pragma unroll
  for (int ci = 0; ci < 18; ci++) {
    U8 ap, bv;
    ap.u = *(const uint4*)&P[l15][ci * 32 + quad * 8];
    bv.u = *(const uint4*)(vrow + ci * 32 + quad * 8);
    acco = __builtin_amdgcn_mfma_f32_16x16x32_bf16(ap.v, bv.v, acco, 0, 0, 0);
  }
#pragma unroll
  for (int i = 0; i < 4; i++) {
    const int q = q0 + quad * 4 + i;
    if (q < NSEQ) {
      ctx[((size_t)b * NSEQ + q) * ND + h * NDH + dh] = acco[i] * inv[i];
    }
  }
}

// ---------------------------------------------------------------------------
// K4: layernorm over D=512, eps=1e-7. (unchanged)
// ---------------------------------------------------------------------------
__global__ __launch_bounds__(256) void lnorm(
    const float* __restrict__ tmp, const float* __restrict__ gamma,
    const float* __restrict__ beta, float* __restrict__ out) {
  __shared__ float sred[256];
  const int row = blockIdx.x;
  const int tid = threadIdx.x;
  const size_t base = (size_t)row * 512;
  const float x0 = tmp[base + tid];
  const float x1 = tmp[base + 256 + tid];

  sred[tid] = x0 + x1;
  __syncthreads();
  for (int o = 128; o > 0; o >>= 1) {
    if (tid < o) sred[tid] += sred[tid + o];
    __syncthreads();
  }
  const float mean = sred[0] * (1.f / 512.f);
  __syncthreads();
  const float d0 = x0 - mean, d1 = x1 - mean;
  sred[tid] = d0 * d0 + d1 * d1;
  __syncthreads();
  for (int o = 128; o > 0; o >>= 1) {
    if (tid < o) sred[tid] += sred[tid + o];
    __syncthreads();
  }
  const float var = sred[0] * (1.f / 512.f);
  const float rstd = rsqrtf(var + 1e-7f);
  out[base + tid] = d0 * rstd * gamma[tid] + beta[tid];
  out[base + 256 + tid] = d1 * rstd * gamma[tid + 256] + beta[tid + 256];
}

// ---------------------------------------------------------------------------
// Workspace: qh + kh (35.4 MB) + vt (17.8 MB, pitch 544) + posb (138 KB)
// + Wt (2 MB) = 55.4 MB. ctx (fp32) lives in d_out; pre-LN tmp (fp32) reuses
// qh+kh (dead after attn); lnorm writes final fp32 to d_out.
// ---------------------------------------------------------------------------
extern "C" void kernel_launch(void* const* d_in, const int* in_sizes, int n_in,
                              void* d_out, int out_size, void* d_ws, size_t ws_size,
                              hipStream_t stream) {
  const float* query = (const float*)d_in[0];
  const float* Wq = (const float*)d_in[1];
  const float* bq = (const float*)d_in[2];
  const float* Wk = (const float*)d_in[3];
  const float* bk = (const float*)d_in[4];
  const float* Wv = (const float*)d_in[5];
  const float* bv = (const float*)d_in[6];
  const float* Wh = (const float*)d_in[7];
  const float* bh = (const float*)d_in[8];
  const float* pos = (const float*)d_in[9];
  const float* gamma = (const float*)d_in[10];
  const float* beta = (const float*)d_in[11];
  const int* vlen = (const int*)d_in[12];

  bf16* ws = (bf16*)d_ws;
  const size_t QSZ = (size_t)NHB * NSEQ * NDH;   // 8,847,360 elems
  const size_t VSZ = (size_t)NHB * NDH * VTP;    // 8,912,896 elems
  bf16* qh = ws;
  bf16* kh = ws + QSZ;
  bf16* vt = ws + 2 * QSZ;
  unsigned short* posb = (unsigned short*)(ws + 2 * QSZ + VSZ);
  unsigned short* Wtb = posb + (size_t)NPOS * NDH;  // 4 x [512][512] bf16
  float* ctx = (float*)d_out;
  float* tmp = (float*)d_ws;  // reuses qh+kh (35.4 MB)
  (void)ws_size;

  pos_cvt<<<dim3(270), 256, 0, stream>>>(pos, posb);
  wcvt<<<dim3(8, 8, 4), 256, 0, stream>>>(Wq, Wk, Wv, Wh, Wtb);
  qkv_mfma<<<dim3(4, 135, 3), 256, 0, stream>>>(query, Wtb, bq, bk, bv, qh, kh, vt);
  attn<<<dim3(34, 256), 256, 0, stream>>>(qh, kh, vt, posb, vlen, ctx);
  out_mfma<<<dim3(4, 135), 256, 0, stream>>>(ctx, Wtb + 3 * (size_t)ND * ND, bh, query, tmp);
  lnorm<<<NM, 256, 0, stream>>>(tmp, gamma, beta, (float*)d_out);
}